// Round 12
// baseline (558.612 us; speedup 1.0000x reference)
//
#include <hip/hip_runtime.h>
#include <math.h>

// PEER: product-key expert retrieval.
// Score path replicates numpy fp32 reference bit-for-bit (sequential-k FMA
// chain for q-GEMM; SSE 4-lane mul/add partials for einsum; fp32 adds for
// combined scores). Selection then matches np exactly. Value path fp64-accum.
// R12: R11 + deeper gather MLP: down phase 2-expert-deep register prefetch,
// up phase depth-8 rotating prefetch. Arithmetic order untouched.

#define DIMV 1024

// ---------------- K1: rmsnorm: fp64 norm, fp32 elementwise x/n*32 ----------
__global__ __launch_bounds__(256) void peer_rmsnorm(const float* __restrict__ x,
                                                    const float* __restrict__ gamma,
                                                    float* __restrict__ xnf)
{
    int t = blockIdx.x;
    int tid = threadIdx.x;
    const float4* xr = (const float4*)(x + (size_t)t * DIMV);
    float4 v = xr[tid];
    double ss = (double)v.x*v.x + (double)v.y*v.y + (double)v.z*v.z + (double)v.w*v.w;
    #pragma unroll
    for (int off = 32; off > 0; off >>= 1) ss += __shfl_xor(ss, off);
    __shared__ double red[4];
    if ((tid & 63) == 0) red[tid >> 6] = ss;
    __syncthreads();
    double tot = red[0] + red[1] + red[2] + red[3];
    float n32 = (float)fmax(sqrt(tot), 1e-12);
    const float4* g4 = (const float4*)gamma;
    float4 gv = g4[tid];
    float4 o;
    o.x = __fmul_rn(__fmul_rn(__fdiv_rn(v.x, n32), gv.x), 32.0f);
    o.y = __fmul_rn(__fmul_rn(__fdiv_rn(v.y, n32), gv.y), 32.0f);
    o.z = __fmul_rn(__fmul_rn(__fdiv_rn(v.z, n32), gv.z), 32.0f);
    o.w = __fmul_rn(__fmul_rn(__fdiv_rn(v.w, n32), gv.w), 32.0f);
    ((float4*)(xnf + (size_t)t * DIMV))[tid] = o;
}

// ------- K2: q = xn @ wq^T, fp32 sequential-k FMA chain (BLAS mimic) -------
// 128x128 tile, K-step 16, double-buffered aligned LDS [16][128]. (R7 exact)
__global__ __launch_bounds__(256) void peer_qgemm(const float* __restrict__ A,
                                                  const float* __restrict__ Bm,
                                                  float* __restrict__ C)
{
    __shared__ float As[2][16][128];
    __shared__ float Bs[2][16][128];
    int tid = threadIdx.x;
    int m0 = blockIdx.y * 128, n0 = blockIdx.x * 128;
    int tx = tid & 15, ty = tid >> 4;
    int lrow = tid >> 1, lk8 = (tid & 1) * 8;   // loader: row, k-octet
    float acc[8][8] = {};
    float4 av0 = *(const float4*)(A  + (long)(m0 + lrow) * 1024 + lk8);
    float4 av1 = *(const float4*)(A  + (long)(m0 + lrow) * 1024 + lk8 + 4);
    float4 bv0 = *(const float4*)(Bm + (long)(n0 + lrow) * 1024 + lk8);
    float4 bv1 = *(const float4*)(Bm + (long)(n0 + lrow) * 1024 + lk8 + 4);
    #pragma unroll
    for (int j = 0; j < 4; j++) {
        As[0][lk8 + j][lrow]     = ((const float*)&av0)[j];
        As[0][lk8 + 4 + j][lrow] = ((const float*)&av1)[j];
        Bs[0][lk8 + j][lrow]     = ((const float*)&bv0)[j];
        Bs[0][lk8 + 4 + j][lrow] = ((const float*)&bv1)[j];
    }
    __syncthreads();
    int cur = 0;
    for (int k0 = 0; k0 < 1024; k0 += 16) {
        bool more = (k0 + 16) < 1024;
        if (more) {                            // in flight under 1024 FMAs
            av0 = *(const float4*)(A  + (long)(m0 + lrow) * 1024 + (k0 + 16 + lk8));
            av1 = *(const float4*)(A  + (long)(m0 + lrow) * 1024 + (k0 + 20 + lk8));
            bv0 = *(const float4*)(Bm + (long)(n0 + lrow) * 1024 + (k0 + 16 + lk8));
            bv1 = *(const float4*)(Bm + (long)(n0 + lrow) * 1024 + (k0 + 20 + lk8));
        }
        #pragma unroll
        for (int kk = 0; kk < 16; kk++) {
            float4 a0 = *(const float4*)&As[cur][kk][ty * 8];
            float4 a1 = *(const float4*)&As[cur][kk][ty * 8 + 4];
            float4 b0 = *(const float4*)&Bs[cur][kk][tx * 4];
            float4 b1 = *(const float4*)&Bs[cur][kk][tx * 4 + 64];
            float ra8[8] = {a0.x,a0.y,a0.z,a0.w,a1.x,a1.y,a1.z,a1.w};
            float rb8[8] = {b0.x,b0.y,b0.z,b0.w,b1.x,b1.y,b1.z,b1.w};
            #pragma unroll
            for (int i = 0; i < 8; i++)
                #pragma unroll
                for (int j = 0; j < 8; j++)
                    acc[i][j] = __fmaf_rn(ra8[i], rb8[j], acc[i][j]);
        }
        if (more) {
            int nxt = cur ^ 1;
            #pragma unroll
            for (int j = 0; j < 4; j++) {
                As[nxt][lk8 + j][lrow]     = ((const float*)&av0)[j];
                As[nxt][lk8 + 4 + j][lrow] = ((const float*)&av1)[j];
                Bs[nxt][lk8 + j][lrow]     = ((const float*)&bv0)[j];
                Bs[nxt][lk8 + 4 + j][lrow] = ((const float*)&bv1)[j];
            }
            __syncthreads();
            cur = nxt;
        }
    }
    #pragma unroll
    for (int i = 0; i < 8; i++) {
        float4 c0 = {acc[i][0], acc[i][1], acc[i][2], acc[i][3]};
        float4 c1 = {acc[i][4], acc[i][5], acc[i][6], acc[i][7]};
        long r = (long)(m0 + ty * 8 + i) * 8192 + n0;
        *(float4*)(C + r + tx * 4)      = c0;
        *(float4*)(C + r + 64 + tx * 4) = c1;
    }
}

// ------- K3: sim via numpy-einsum SSE pattern: 4-lane mul/add partials -----
__global__ __launch_bounds__(256) void peer_sim(const float* __restrict__ qf,
                                                const float* __restrict__ keys,
                                                float* __restrict__ simf)
{
    int tb = blockIdx.x;      // 0..63 (token tile of 16)
    int z  = blockIdx.y;      // 0..15
    int h = z & 7, p = z >> 3;
    int tid = threadIdx.x;
    __shared__ float4 qs[16][128];
    int t0 = tb * 16;
    long qbase = (long)h * 512 + (long)p * 4096;
    int row = tid >> 4, c0 = (tid & 15) * 8;
    const float4* qrow = (const float4*)(qf + (long)(t0 + row) * 8192 + qbase);
    #pragma unroll
    for (int u = 0; u < 8; u++) qs[row][c0 + u] = qrow[c0 + u];
    __syncthreads();
    int k = tid;
    const float4* krow = (const float4*)(keys + (long)h * 262144 + (long)k * 1024 + (long)p * 512);
    float pa[16][4] = {};
    for (int d4 = 0; d4 < 128; d4++) {
        float4 kv = krow[d4];
        #pragma unroll
        for (int tt = 0; tt < 16; tt++) {
            float4 qv = qs[tt][d4];
            pa[tt][0] = __fadd_rn(pa[tt][0], __fmul_rn(qv.x, kv.x));
            pa[tt][1] = __fadd_rn(pa[tt][1], __fmul_rn(qv.y, kv.y));
            pa[tt][2] = __fadd_rn(pa[tt][2], __fmul_rn(qv.z, kv.z));
            pa[tt][3] = __fadd_rn(pa[tt][3], __fmul_rn(qv.w, kv.w));
        }
    }
    #pragma unroll
    for (int tt = 0; tt < 16; tt++) {
        float s = __fadd_rn(__fadd_rn(pa[tt][0], pa[tt][2]),
                            __fadd_rn(pa[tt][1], pa[tt][3]));
        simf[(long)(t0 + tt) * 4096 + (long)p * 2048 + h * 256 + k] = s;
    }
}

// ---------------- K4: two-stage top-16 on fp32 sims (one wave/(t,h)) -------
__device__ inline void peer_select16(float v[4], int lane, float* outv, int* outi)
{
    for (int iter = 0; iter < 16; iter++) {
        float bv = -INFINITY; int bk = 1 << 30;
        #pragma unroll
        for (int i = 0; i < 4; i++) {
            int k = i * 64 + lane;
            if (v[i] > bv || (v[i] == bv && k < bk)) { bv = v[i]; bk = k; }
        }
        #pragma unroll
        for (int off = 32; off > 0; off >>= 1) {
            float ov = __shfl_xor(bv, off);
            int   ok = __shfl_xor(bk, off);
            if (ov > bv || (ov == bv && ok < bk)) { bv = ov; bk = ok; }
        }
        if (lane == 0) { outv[iter] = bv; outi[iter] = bk; }
        __syncthreads();
        if ((bk & 63) == lane) v[bk >> 6] = -INFINITY;
    }
}

__global__ __launch_bounds__(64) void peer_topk(const float* __restrict__ sim,
                                                float* __restrict__ wsel,
                                                int* __restrict__ esel)
{
    int b = blockIdx.x;           // b = t*8 + h
    int t = b >> 3, h = b & 7;
    int lane = threadIdx.x;
    const float* simx = sim + (size_t)t * 4096 + h * 256;   // p=0
    const float* simy = simx + 2048;                        // p=1
    __shared__ float sxv[16]; __shared__ int sxi[16];
    __shared__ float syv[16]; __shared__ int syi[16];
    __shared__ float cv[16];  __shared__ int cf[16];
    float v[4];
    #pragma unroll
    for (int i = 0; i < 4; i++) v[i] = simx[i*64 + lane];
    peer_select16(v, lane, sxv, sxi);
    __syncthreads();
    #pragma unroll
    for (int i = 0; i < 4; i++) v[i] = simy[i*64 + lane];
    peer_select16(v, lane, syv, syi);
    __syncthreads();
    #pragma unroll
    for (int i = 0; i < 4; i++) {
        int f = i*64 + lane;
        v[i] = __fadd_rn(sxv[f >> 4], syv[f & 15]);
    }
    peer_select16(v, lane, cv, cf);
    __syncthreads();
    double m = (double)cv[0];
    double w = (lane < 16) ? exp((double)cv[lane] - m) : 0.0;
    double Z = w;
    #pragma unroll
    for (int off = 32; off > 0; off >>= 1) Z += __shfl_xor(Z, off);
    if (lane < 16) {
        int f = cf[lane];
        esel[b * 16 + lane] = sxi[f >> 4] * 256 + syi[f & 15];
        wsel[b * 16 + lane] = (float)(w / Z);
    }
}

// ------- K5: fused gather: g = gelu(xn.wd)*w, out = sum g * wu -------------
// 256 thr/block, 1024 blocks. Down: 2-expert-deep register prefetch.
// Up: depth-8 rotating prefetch. fp64 accumulation chains unchanged.
__global__ __launch_bounds__(256) void peer_downup(const float* __restrict__ xn,
                                                   const float* __restrict__ table_down,
                                                   const float* __restrict__ table_up,
                                                   const int* __restrict__ esel,
                                                   const float* __restrict__ wsel,
                                                   float* __restrict__ out)
{
    int t = blockIdx.x;
    int tid = threadIdx.x;
    int wid = tid >> 6, lane = tid & 63;
    __shared__ float4 xs[256];
    __shared__ float  gs[128];
    __shared__ int    es[128];
    if (tid < 128) es[tid] = esel[t * 128 + tid];
    xs[tid] = ((const float4*)(xn + (size_t)t * DIMV))[tid];
    __syncthreads();
    // ---- down phase: wave wid owns experts wid*32..+31, 2-deep prefetch ----
    int base = wid * 32;
    const float4* dr0 = (const float4*)(table_down + (size_t)es[base] * DIMV);
    const float4* dr1 = (const float4*)(table_down + (size_t)es[base + 1] * DIMV);
    float4 p0 = dr0[lane], p1 = dr0[64 + lane], p2 = dr0[128 + lane], p3 = dr0[192 + lane];
    float4 q0 = dr1[lane], q1 = dr1[64 + lane], q2 = dr1[128 + lane], q3 = dr1[192 + lane];
    for (int jj = 0; jj < 32; jj++) {
        float4 c0 = p0, c1 = p1, c2 = p2, c3 = p3;
        p0 = q0; p1 = q1; p2 = q2; p3 = q3;
        if (jj < 30) {
            const float4* nr = (const float4*)(table_down + (size_t)es[base + jj + 2] * DIMV);
            q0 = nr[lane]; q1 = nr[64 + lane]; q2 = nr[128 + lane]; q3 = nr[192 + lane];
        }
        float4 a0 = xs[lane], a1 = xs[64 + lane], a2 = xs[128 + lane], a3 = xs[192 + lane];
        double acc = 0.0;
        acc = fma((double)a0.x, (double)c0.x, acc);
        acc = fma((double)a0.y, (double)c0.y, acc);
        acc = fma((double)a0.z, (double)c0.z, acc);
        acc = fma((double)a0.w, (double)c0.w, acc);
        acc = fma((double)a1.x, (double)c1.x, acc);
        acc = fma((double)a1.y, (double)c1.y, acc);
        acc = fma((double)a1.z, (double)c1.z, acc);
        acc = fma((double)a1.w, (double)c1.w, acc);
        acc = fma((double)a2.x, (double)c2.x, acc);
        acc = fma((double)a2.y, (double)c2.y, acc);
        acc = fma((double)a2.z, (double)c2.z, acc);
        acc = fma((double)a2.w, (double)c2.w, acc);
        acc = fma((double)a3.x, (double)c3.x, acc);
        acc = fma((double)a3.y, (double)c3.y, acc);
        acc = fma((double)a3.z, (double)c3.z, acc);
        acc = fma((double)a3.w, (double)c3.w, acc);
        #pragma unroll
        for (int off = 32; off > 0; off >>= 1) acc += __shfl_xor(acc, off);
        if (lane == 0) {
            double hv = acc;
            double ge = 0.5 * hv * (1.0 + erf(hv * 0.70710678118654752));
            gs[base + jj] = (float)(ge * (double)wsel[t * 128 + base + jj]);
        }
    }
    __syncthreads();
    // ---- up phase: depth-8 rotating prefetch (static indices) ----
    int dbase = tid * 4;
    double b0 = 0, b1 = 0, b2 = 0, b3 = 0;
    float4 u0 = *(const float4*)(table_up + (size_t)es[0] * DIMV + dbase);
    float4 u1 = *(const float4*)(table_up + (size_t)es[1] * DIMV + dbase);
    float4 u2 = *(const float4*)(table_up + (size_t)es[2] * DIMV + dbase);
    float4 u3 = *(const float4*)(table_up + (size_t)es[3] * DIMV + dbase);
    float4 u4 = *(const float4*)(table_up + (size_t)es[4] * DIMV + dbase);
    float4 u5 = *(const float4*)(table_up + (size_t)es[5] * DIMV + dbase);
    float4 u6 = *(const float4*)(table_up + (size_t)es[6] * DIMV + dbase);
    float4 u7 = *(const float4*)(table_up + (size_t)es[7] * DIMV + dbase);
    for (int j = 0; j < 128; j += 8) {
        float4 c0 = u0, c1 = u1, c2 = u2, c3 = u3;
        float4 c4 = u4, c5 = u5, c6 = u6, c7 = u7;
        if (j + 8 < 128) {
            u0 = *(const float4*)(table_up + (size_t)es[j + 8]  * DIMV + dbase);
            u1 = *(const float4*)(table_up + (size_t)es[j + 9]  * DIMV + dbase);
            u2 = *(const float4*)(table_up + (size_t)es[j + 10] * DIMV + dbase);
            u3 = *(const float4*)(table_up + (size_t)es[j + 11] * DIMV + dbase);
            u4 = *(const float4*)(table_up + (size_t)es[j + 12] * DIMV + dbase);
            u5 = *(const float4*)(table_up + (size_t)es[j + 13] * DIMV + dbase);
            u6 = *(const float4*)(table_up + (size_t)es[j + 14] * DIMV + dbase);
            u7 = *(const float4*)(table_up + (size_t)es[j + 15] * DIMV + dbase);
        }
        double g0 = (double)gs[j],     g1 = (double)gs[j + 1];
        double g2 = (double)gs[j + 2], g3 = (double)gs[j + 3];
        double g4 = (double)gs[j + 4], g5 = (double)gs[j + 5];
        double g6 = (double)gs[j + 6], g7 = (double)gs[j + 7];
        b0 = fma(g0, (double)c0.x, b0); b1 = fma(g0, (double)c0.y, b1);
        b2 = fma(g0, (double)c0.z, b2); b3 = fma(g0, (double)c0.w, b3);
        b0 = fma(g1, (double)c1.x, b0); b1 = fma(g1, (double)c1.y, b1);
        b2 = fma(g1, (double)c1.z, b2); b3 = fma(g1, (double)c1.w, b3);
        b0 = fma(g2, (double)c2.x, b0); b1 = fma(g2, (double)c2.y, b1);
        b2 = fma(g2, (double)c2.z, b2); b3 = fma(g2, (double)c2.w, b3);
        b0 = fma(g3, (double)c3.x, b0); b1 = fma(g3, (double)c3.y, b1);
        b2 = fma(g3, (double)c3.z, b2); b3 = fma(g3, (double)c3.w, b3);
        b0 = fma(g4, (double)c4.x, b0); b1 = fma(g4, (double)c4.y, b1);
        b2 = fma(g4, (double)c4.z, b2); b3 = fma(g4, (double)c4.w, b3);
        b0 = fma(g5, (double)c5.x, b0); b1 = fma(g5, (double)c5.y, b1);
        b2 = fma(g5, (double)c5.z, b2); b3 = fma(g5, (double)c5.w, b3);
        b0 = fma(g6, (double)c6.x, b0); b1 = fma(g6, (double)c6.y, b1);
        b2 = fma(g6, (double)c6.z, b2); b3 = fma(g6, (double)c6.w, b3);
        b0 = fma(g7, (double)c7.x, b0); b1 = fma(g7, (double)c7.y, b1);
        b2 = fma(g7, (double)c7.z, b2); b3 = fma(g7, (double)c7.w, b3);
    }
    float4 o = {(float)b0, (float)b1, (float)b2, (float)b3};
    *(float4*)(out + (size_t)t * DIMV + dbase) = o;
}

extern "C" void kernel_launch(void* const* d_in, const int* in_sizes, int n_in,
                              void* d_out, int out_size, void* d_ws, size_t ws_size,
                              hipStream_t stream)
{
    const float* x          = (const float*)d_in[0];
    const float* gamma      = (const float*)d_in[1];
    const float* wq         = (const float*)d_in[2];
    const float* keys       = (const float*)d_in[3];
    const float* table_down = (const float*)d_in[4];
    const float* table_up   = (const float*)d_in[5];
    float* out = (float*)d_out;
    char* wsb  = (char*)d_ws;

    // workspace layout (bytes)
    float* xnf  = (float*)(wsb);                        //  4 MB [1024 x 1024]
    float* qf   = (float*)(wsb + (4ull<<20));           // 32 MB [1024 x 8192]
    float* simf = (float*)(wsb + (36ull<<20));          // 16 MB [1024 x 4096]
    float* wsel = (float*)(wsb + (52ull<<20));          // 512 KB
    int*   esel = (int*)  (wsb + (52ull<<20) + (512ull<<10));
    if (ws_size < (54ull << 20)) return;  // need 54 MB scratch

    // 1) rmsnorm (fp64 norm -> fp32 scale, mimics np fp32 elementwise)
    peer_rmsnorm<<<1024, 256, 0, stream>>>(x, gamma, xnf);

    // 2) q[t,r] = sum_D xn[t,D]*wq[r,D], fp32 sequential-FMA (BLAS mimic)
    peer_qgemm<<<dim3(64, 8, 1), 256, 0, stream>>>(xnf, wq, qf);

    // 3) sim[t, p*2048+h*256+k] via einsum-SSE 4-lane fp32 partials
    peer_sim<<<dim3(64, 16, 1), 256, 0, stream>>>(qf, keys, simf);

    // 4) two-stage top-16 + softmax weights + expert ids
    peer_topk<<<8192, 64, 0, stream>>>(simf, wsel, esel);

    // 5) fused: g = gelu(xn . wd[e]) * w ; out = sum_j g_j * wu[e_j]
    peer_downup<<<1024, 256, 0, stream>>>(xnf, table_down, table_up,
                                          esel, wsel, out);
}

// Round 13
// 539.742 us; speedup vs baseline: 1.0350x; 1.0350x over previous
//
#include <hip/hip_runtime.h>
#include <math.h>

// PEER: product-key expert retrieval.
// Score path replicates numpy fp32 reference bit-for-bit (sequential-k FMA
// chain for q-GEMM; SSE 4-lane mul/add partials for einsum; fp32 adds for
// combined scores). Selection then matches np exactly. Value path fp64-accum.
// R13 = R11 exact revert (best measured: 540.9 us).
//   qgemm: R7 structure - 256 thr, 128x128 tile, 8x8/thread, K-step 16,
//          32KB dbuf aligned LDS, tx*4/+64 frag map (210 us, VALU 66% =
//          LDS-port ceiling 67%). R8/R9/R10 structural variants all lost.
//   downup: R9 structure - 1-deep down prefetch w/ reg-cached xs, depth-4
//           up rotation (R12's deeper MLP regressed: VGPR pressure, gather
//           already at random-row DRAM efficiency ceiling ~4 TB/s).

#define DIMV 1024

// ---------------- K1: rmsnorm: fp64 norm, fp32 elementwise x/n*32 ----------
__global__ __launch_bounds__(256) void peer_rmsnorm(const float* __restrict__ x,
                                                    const float* __restrict__ gamma,
                                                    float* __restrict__ xnf)
{
    int t = blockIdx.x;
    int tid = threadIdx.x;
    const float4* xr = (const float4*)(x + (size_t)t * DIMV);
    float4 v = xr[tid];
    double ss = (double)v.x*v.x + (double)v.y*v.y + (double)v.z*v.z + (double)v.w*v.w;
    #pragma unroll
    for (int off = 32; off > 0; off >>= 1) ss += __shfl_xor(ss, off);
    __shared__ double red[4];
    if ((tid & 63) == 0) red[tid >> 6] = ss;
    __syncthreads();
    double tot = red[0] + red[1] + red[2] + red[3];
    float n32 = (float)fmax(sqrt(tot), 1e-12);
    const float4* g4 = (const float4*)gamma;
    float4 gv = g4[tid];
    float4 o;
    o.x = __fmul_rn(__fmul_rn(__fdiv_rn(v.x, n32), gv.x), 32.0f);
    o.y = __fmul_rn(__fmul_rn(__fdiv_rn(v.y, n32), gv.y), 32.0f);
    o.z = __fmul_rn(__fmul_rn(__fdiv_rn(v.z, n32), gv.z), 32.0f);
    o.w = __fmul_rn(__fmul_rn(__fdiv_rn(v.w, n32), gv.w), 32.0f);
    ((float4*)(xnf + (size_t)t * DIMV))[tid] = o;
}

// ------- K2: q = xn @ wq^T, fp32 sequential-k FMA chain (BLAS mimic) -------
// 128x128 tile, K-step 16, double-buffered aligned LDS [16][128]. (R7 exact)
// Thread (tx,ty): rows m0+ty*8+i, cols n0+tx*4+j and n0+64+tx*4+j.
__global__ __launch_bounds__(256) void peer_qgemm(const float* __restrict__ A,
                                                  const float* __restrict__ Bm,
                                                  float* __restrict__ C)
{
    __shared__ float As[2][16][128];
    __shared__ float Bs[2][16][128];
    int tid = threadIdx.x;
    int m0 = blockIdx.y * 128, n0 = blockIdx.x * 128;
    int tx = tid & 15, ty = tid >> 4;
    int lrow = tid >> 1, lk8 = (tid & 1) * 8;   // loader: row, k-octet
    float acc[8][8] = {};
    float4 av0 = *(const float4*)(A  + (long)(m0 + lrow) * 1024 + lk8);
    float4 av1 = *(const float4*)(A  + (long)(m0 + lrow) * 1024 + lk8 + 4);
    float4 bv0 = *(const float4*)(Bm + (long)(n0 + lrow) * 1024 + lk8);
    float4 bv1 = *(const float4*)(Bm + (long)(n0 + lrow) * 1024 + lk8 + 4);
    #pragma unroll
    for (int j = 0; j < 4; j++) {
        As[0][lk8 + j][lrow]     = ((const float*)&av0)[j];
        As[0][lk8 + 4 + j][lrow] = ((const float*)&av1)[j];
        Bs[0][lk8 + j][lrow]     = ((const float*)&bv0)[j];
        Bs[0][lk8 + 4 + j][lrow] = ((const float*)&bv1)[j];
    }
    __syncthreads();
    int cur = 0;
    for (int k0 = 0; k0 < 1024; k0 += 16) {
        bool more = (k0 + 16) < 1024;
        if (more) {                            // in flight under 1024 FMAs
            av0 = *(const float4*)(A  + (long)(m0 + lrow) * 1024 + (k0 + 16 + lk8));
            av1 = *(const float4*)(A  + (long)(m0 + lrow) * 1024 + (k0 + 20 + lk8));
            bv0 = *(const float4*)(Bm + (long)(n0 + lrow) * 1024 + (k0 + 16 + lk8));
            bv1 = *(const float4*)(Bm + (long)(n0 + lrow) * 1024 + (k0 + 20 + lk8));
        }
        #pragma unroll
        for (int kk = 0; kk < 16; kk++) {
            float4 a0 = *(const float4*)&As[cur][kk][ty * 8];
            float4 a1 = *(const float4*)&As[cur][kk][ty * 8 + 4];
            float4 b0 = *(const float4*)&Bs[cur][kk][tx * 4];
            float4 b1 = *(const float4*)&Bs[cur][kk][tx * 4 + 64];
            float ra8[8] = {a0.x,a0.y,a0.z,a0.w,a1.x,a1.y,a1.z,a1.w};
            float rb8[8] = {b0.x,b0.y,b0.z,b0.w,b1.x,b1.y,b1.z,b1.w};
            #pragma unroll
            for (int i = 0; i < 8; i++)
                #pragma unroll
                for (int j = 0; j < 8; j++)
                    acc[i][j] = __fmaf_rn(ra8[i], rb8[j], acc[i][j]);
        }
        if (more) {
            int nxt = cur ^ 1;
            #pragma unroll
            for (int j = 0; j < 4; j++) {
                As[nxt][lk8 + j][lrow]     = ((const float*)&av0)[j];
                As[nxt][lk8 + 4 + j][lrow] = ((const float*)&av1)[j];
                Bs[nxt][lk8 + j][lrow]     = ((const float*)&bv0)[j];
                Bs[nxt][lk8 + 4 + j][lrow] = ((const float*)&bv1)[j];
            }
            __syncthreads();
            cur = nxt;
        }
    }
    #pragma unroll
    for (int i = 0; i < 8; i++) {
        float4 c0 = {acc[i][0], acc[i][1], acc[i][2], acc[i][3]};
        float4 c1 = {acc[i][4], acc[i][5], acc[i][6], acc[i][7]};
        long r = (long)(m0 + ty * 8 + i) * 8192 + n0;
        *(float4*)(C + r + tx * 4)      = c0;
        *(float4*)(C + r + 64 + tx * 4) = c1;
    }
}

// ------- K3: sim via numpy-einsum SSE pattern: 4-lane mul/add partials -----
__global__ __launch_bounds__(256) void peer_sim(const float* __restrict__ qf,
                                                const float* __restrict__ keys,
                                                float* __restrict__ simf)
{
    int tb = blockIdx.x;      // 0..63 (token tile of 16)
    int z  = blockIdx.y;      // 0..15
    int h = z & 7, p = z >> 3;
    int tid = threadIdx.x;
    __shared__ float4 qs[16][128];
    int t0 = tb * 16;
    long qbase = (long)h * 512 + (long)p * 4096;
    int row = tid >> 4, c0 = (tid & 15) * 8;
    const float4* qrow = (const float4*)(qf + (long)(t0 + row) * 8192 + qbase);
    #pragma unroll
    for (int u = 0; u < 8; u++) qs[row][c0 + u] = qrow[c0 + u];
    __syncthreads();
    int k = tid;
    const float4* krow = (const float4*)(keys + (long)h * 262144 + (long)k * 1024 + (long)p * 512);
    float pa[16][4] = {};
    for (int d4 = 0; d4 < 128; d4++) {
        float4 kv = krow[d4];
        #pragma unroll
        for (int tt = 0; tt < 16; tt++) {
            float4 qv = qs[tt][d4];
            pa[tt][0] = __fadd_rn(pa[tt][0], __fmul_rn(qv.x, kv.x));
            pa[tt][1] = __fadd_rn(pa[tt][1], __fmul_rn(qv.y, kv.y));
            pa[tt][2] = __fadd_rn(pa[tt][2], __fmul_rn(qv.z, kv.z));
            pa[tt][3] = __fadd_rn(pa[tt][3], __fmul_rn(qv.w, kv.w));
        }
    }
    #pragma unroll
    for (int tt = 0; tt < 16; tt++) {
        float s = __fadd_rn(__fadd_rn(pa[tt][0], pa[tt][2]),
                            __fadd_rn(pa[tt][1], pa[tt][3]));
        simf[(long)(t0 + tt) * 4096 + (long)p * 2048 + h * 256 + k] = s;
    }
}

// ---------------- K4: two-stage top-16 on fp32 sims (one wave/(t,h)) -------
__device__ inline void peer_select16(float v[4], int lane, float* outv, int* outi)
{
    for (int iter = 0; iter < 16; iter++) {
        float bv = -INFINITY; int bk = 1 << 30;
        #pragma unroll
        for (int i = 0; i < 4; i++) {
            int k = i * 64 + lane;
            if (v[i] > bv || (v[i] == bv && k < bk)) { bv = v[i]; bk = k; }
        }
        #pragma unroll
        for (int off = 32; off > 0; off >>= 1) {
            float ov = __shfl_xor(bv, off);
            int   ok = __shfl_xor(bk, off);
            if (ov > bv || (ov == bv && ok < bk)) { bv = ov; bk = ok; }
        }
        if (lane == 0) { outv[iter] = bv; outi[iter] = bk; }
        __syncthreads();
        if ((bk & 63) == lane) v[bk >> 6] = -INFINITY;
    }
}

__global__ __launch_bounds__(64) void peer_topk(const float* __restrict__ sim,
                                                float* __restrict__ wsel,
                                                int* __restrict__ esel)
{
    int b = blockIdx.x;           // b = t*8 + h
    int t = b >> 3, h = b & 7;
    int lane = threadIdx.x;
    const float* simx = sim + (size_t)t * 4096 + h * 256;   // p=0
    const float* simy = simx + 2048;                        // p=1
    __shared__ float sxv[16]; __shared__ int sxi[16];
    __shared__ float syv[16]; __shared__ int syi[16];
    __shared__ float cv[16];  __shared__ int cf[16];
    float v[4];
    #pragma unroll
    for (int i = 0; i < 4; i++) v[i] = simx[i*64 + lane];
    peer_select16(v, lane, sxv, sxi);
    __syncthreads();
    #pragma unroll
    for (int i = 0; i < 4; i++) v[i] = simy[i*64 + lane];
    peer_select16(v, lane, syv, syi);
    __syncthreads();
    #pragma unroll
    for (int i = 0; i < 4; i++) {
        int f = i*64 + lane;
        v[i] = __fadd_rn(sxv[f >> 4], syv[f & 15]);
    }
    peer_select16(v, lane, cv, cf);
    __syncthreads();
    double m = (double)cv[0];
    double w = (lane < 16) ? exp((double)cv[lane] - m) : 0.0;
    double Z = w;
    #pragma unroll
    for (int off = 32; off > 0; off >>= 1) Z += __shfl_xor(Z, off);
    if (lane < 16) {
        int f = cf[lane];
        esel[b * 16 + lane] = sxi[f >> 4] * 256 + syi[f & 15];
        wsel[b * 16 + lane] = (float)(w / Z);
    }
}

// ------- K5: fused gather: g = gelu(xn.wd)*w, out = sum g * wu -------------
// R9 exact: 256 thr/block, 1024 blocks; register prefetch pipelines.
__global__ __launch_bounds__(256) void peer_downup(const float* __restrict__ xn,
                                                   const float* __restrict__ table_down,
                                                   const float* __restrict__ table_up,
                                                   const int* __restrict__ esel,
                                                   const float* __restrict__ wsel,
                                                   float* __restrict__ out)
{
    int t = blockIdx.x;
    int tid = threadIdx.x;
    int wid = tid >> 6, lane = tid & 63;
    __shared__ float4 xs[256];
    __shared__ float  gs[128];
    __shared__ int    es[128];
    if (tid < 128) es[tid] = esel[t * 128 + tid];
    xs[tid] = ((const float4*)(xn + (size_t)t * DIMV))[tid];
    __syncthreads();
    // ---- down phase: wave wid owns experts wid*32..+31, 1-deep prefetch ----
    int base = wid * 32;
    const float4* dr = (const float4*)(table_down + (size_t)es[base] * DIMV);
    float4 p0 = dr[lane], p1 = dr[64 + lane], p2 = dr[128 + lane], p3 = dr[192 + lane];
    float4 a0 = xs[lane], a1 = xs[64 + lane], a2 = xs[128 + lane], a3 = xs[192 + lane];
    for (int jj = 0; jj < 32; jj++) {
        float4 c0 = p0, c1 = p1, c2 = p2, c3 = p3;
        if (jj < 31) {
            const float4* nr = (const float4*)(table_down + (size_t)es[base + jj + 1] * DIMV);
            p0 = nr[lane]; p1 = nr[64 + lane]; p2 = nr[128 + lane]; p3 = nr[192 + lane];
        }
        double acc = 0.0;
        acc = fma((double)a0.x, (double)c0.x, acc);
        acc = fma((double)a0.y, (double)c0.y, acc);
        acc = fma((double)a0.z, (double)c0.z, acc);
        acc = fma((double)a0.w, (double)c0.w, acc);
        acc = fma((double)a1.x, (double)c1.x, acc);
        acc = fma((double)a1.y, (double)c1.y, acc);
        acc = fma((double)a1.z, (double)c1.z, acc);
        acc = fma((double)a1.w, (double)c1.w, acc);
        acc = fma((double)a2.x, (double)c2.x, acc);
        acc = fma((double)a2.y, (double)c2.y, acc);
        acc = fma((double)a2.z, (double)c2.z, acc);
        acc = fma((double)a2.w, (double)c2.w, acc);
        acc = fma((double)a3.x, (double)c3.x, acc);
        acc = fma((double)a3.y, (double)c3.y, acc);
        acc = fma((double)a3.z, (double)c3.z, acc);
        acc = fma((double)a3.w, (double)c3.w, acc);
        #pragma unroll
        for (int off = 32; off > 0; off >>= 1) acc += __shfl_xor(acc, off);
        if (lane == 0) {
            double hv = acc;
            double ge = 0.5 * hv * (1.0 + erf(hv * 0.70710678118654752));
            gs[base + jj] = (float)(ge * (double)wsel[t * 128 + base + jj]);
        }
    }
    __syncthreads();
    // ---- up phase: depth-4 rotating prefetch (static indices) ----
    int dbase = tid * 4;
    double b0 = 0, b1 = 0, b2 = 0, b3 = 0;
    float4 u0 = *(const float4*)(table_up + (size_t)es[0] * DIMV + dbase);
    float4 u1 = *(const float4*)(table_up + (size_t)es[1] * DIMV + dbase);
    float4 u2 = *(const float4*)(table_up + (size_t)es[2] * DIMV + dbase);
    float4 u3 = *(const float4*)(table_up + (size_t)es[3] * DIMV + dbase);
    for (int j = 0; j < 128; j += 4) {
        float4 c0 = u0, c1 = u1, c2 = u2, c3 = u3;
        if (j + 4 < 128) {
            u0 = *(const float4*)(table_up + (size_t)es[j + 4] * DIMV + dbase);
            u1 = *(const float4*)(table_up + (size_t)es[j + 5] * DIMV + dbase);
            u2 = *(const float4*)(table_up + (size_t)es[j + 6] * DIMV + dbase);
            u3 = *(const float4*)(table_up + (size_t)es[j + 7] * DIMV + dbase);
        }
        double g0 = (double)gs[j],     g1 = (double)gs[j + 1];
        double g2 = (double)gs[j + 2], g3 = (double)gs[j + 3];
        b0 = fma(g0, (double)c0.x, b0); b1 = fma(g0, (double)c0.y, b1);
        b2 = fma(g0, (double)c0.z, b2); b3 = fma(g0, (double)c0.w, b3);
        b0 = fma(g1, (double)c1.x, b0); b1 = fma(g1, (double)c1.y, b1);
        b2 = fma(g1, (double)c1.z, b2); b3 = fma(g1, (double)c1.w, b3);
        b0 = fma(g2, (double)c2.x, b0); b1 = fma(g2, (double)c2.y, b1);
        b2 = fma(g2, (double)c2.z, b2); b3 = fma(g2, (double)c2.w, b3);
        b0 = fma(g3, (double)c3.x, b0); b1 = fma(g3, (double)c3.y, b1);
        b2 = fma(g3, (double)c3.z, b2); b3 = fma(g3, (double)c3.w, b3);
    }
    float4 o = {(float)b0, (float)b1, (float)b2, (float)b3};
    *(float4*)(out + (size_t)t * DIMV + dbase) = o;
}

extern "C" void kernel_launch(void* const* d_in, const int* in_sizes, int n_in,
                              void* d_out, int out_size, void* d_ws, size_t ws_size,
                              hipStream_t stream)
{
    const float* x          = (const float*)d_in[0];
    const float* gamma      = (const float*)d_in[1];
    const float* wq         = (const float*)d_in[2];
    const float* keys       = (const float*)d_in[3];
    const float* table_down = (const float*)d_in[4];
    const float* table_up   = (const float*)d_in[5];
    float* out = (float*)d_out;
    char* wsb  = (char*)d_ws;

    // workspace layout (bytes)
    float* xnf  = (float*)(wsb);                        //  4 MB [1024 x 1024]
    float* qf   = (float*)(wsb + (4ull<<20));           // 32 MB [1024 x 8192]
    float* simf = (float*)(wsb + (36ull<<20));          // 16 MB [1024 x 4096]
    float* wsel = (float*)(wsb + (52ull<<20));          // 512 KB
    int*   esel = (int*)  (wsb + (52ull<<20) + (512ull<<10));
    if (ws_size < (54ull << 20)) return;  // need 54 MB scratch

    // 1) rmsnorm (fp64 norm -> fp32 scale, mimics np fp32 elementwise)
    peer_rmsnorm<<<1024, 256, 0, stream>>>(x, gamma, xnf);

    // 2) q[t,r] = sum_D xn[t,D]*wq[r,D], fp32 sequential-FMA (BLAS mimic)
    peer_qgemm<<<dim3(64, 8, 1), 256, 0, stream>>>(xnf, wq, qf);

    // 3) sim[t, p*2048+h*256+k] via einsum-SSE 4-lane fp32 partials
    peer_sim<<<dim3(64, 16, 1), 256, 0, stream>>>(qf, keys, simf);

    // 4) two-stage top-16 + softmax weights + expert ids
    peer_topk<<<8192, 64, 0, stream>>>(simf, wsel, esel);

    // 5) fused: g = gelu(xn . wd[e]) * w ; out = sum_j g_j * wu[e_j]
    peer_downup<<<1024, 256, 0, stream>>>(xnf, table_down, table_up,
                                          esel, wsel, out);
}